// Round 1
// baseline (260.100 us; speedup 1.0000x reference)
//
#include <hip/hip_runtime.h>
#include <hip/hip_bf16.h>

#define HID    128
#define VOCAB  1000
#define N_CAT  200000
#define N_CONT 150000
#define N_TXN  150000
#define F_TXN  371
#define BK     32
#define NSTEP  12      // 12*32 = 384 >= 371
#define BM     128
#define APAD   40      // LDS row stride in shorts: 80B = 5*16B -> b128-aligned rows

typedef __attribute__((ext_vector_type(8))) short bf16x8;
typedef __attribute__((ext_vector_type(4))) float f32x4;

__device__ __forceinline__ unsigned short f2bf(float x) {
    union { float f; unsigned u; } c; c.f = x;
    unsigned r = c.u + 0x7FFF + ((c.u >> 16) & 1);   // RNE
    return (unsigned short)(r >> 16);
}

// ---- categorical gather: out[i] = tables[tid[i]*VOCAB + vid[i]] ----
__global__ __launch_bounds__(256) void cat_kernel(
    const float* __restrict__ tables, const int* __restrict__ tids,
    const int* __restrict__ vids, float* __restrict__ out)
{
    int tid = blockIdx.x * 256 + threadIdx.x;
    int row = tid >> 5;               // 32 lanes per row
    int h   = (tid & 31) << 2;        // float4
    long src = ((long)tids[row] * VOCAB + vids[row]) * HID + h;
    f32x4 v = *reinterpret_cast<const f32x4*>(tables + src);
    *reinterpret_cast<f32x4*>(out + (long)row * HID + h) = v;
}

// ---- continuous: out[i] = v[i]*w[t] + b[t] ----
__global__ __launch_bounds__(256) void cont_kernel(
    const float* __restrict__ w, const float* __restrict__ b,
    const float* __restrict__ vals, const int* __restrict__ tids,
    float* __restrict__ out)
{
    int tid = blockIdx.x * 256 + threadIdx.x;
    int row = tid >> 5;
    int h   = (tid & 31) << 2;
    int t   = tids[row];
    float v = vals[row];
    f32x4 wv = *reinterpret_cast<const f32x4*>(w + t * HID + h);
    f32x4 bv = *reinterpret_cast<const f32x4*>(b + t * HID + h);
    f32x4 r  = v * wv + bv;
    *reinterpret_cast<f32x4*>(out + (long)(N_CAT + row) * HID + h) = r;
}

// ---- txn GEMM: [150000 x 371] @ [371 x 128] + bias, bf16 MFMA ----
__global__ __launch_bounds__(256) void txn_kernel(
    const float* __restrict__ feats, const float* __restrict__ w,
    const float* __restrict__ bias, float* __restrict__ out)
{
    __shared__ __align__(16) unsigned short Ash[2][BM][APAD];   // [m][k] row-major
    __shared__ __align__(16) unsigned short Bsh[2][HID][APAD];  // [n][k] = w^T

    const int t    = threadIdx.x;
    const int lane = t & 63;
    const int wid  = t >> 6;
    const int wr   = wid >> 1, wc = wid & 1;      // 2x2 wave grid, 64x64 each
    const int blockM = blockIdx.x * BM;

    float ar[16], br[16];

    auto load_regs = [&](int step) {
        const int k0 = step * BK;
        // A: 128x32 elems; 16 consecutive lanes share a row, walk k (coalesced)
        #pragma unroll
        for (int it = 0; it < 8; ++it) {
            int e = it * 512 + t * 2;
            int k = e & 31;
            int m = e >> 5;
            int row = blockM + m;
            int c0  = k0 + k;
            bool rv = (row < N_TXN);
            ar[it*2]   = (rv && c0     < F_TXN) ? feats[(long)row * F_TXN + c0]     : 0.f;
            ar[it*2+1] = (rv && c0 + 1 < F_TXN) ? feats[(long)row * F_TXN + c0 + 1] : 0.f;
        }
        // B: 32x128 elems staged transposed; 16 consecutive lanes share n, walk k
        #pragma unroll
        for (int it = 0; it < 8; ++it) {
            int p = it * 256 + t;
            int n = p >> 4;
            int k = (p & 15) * 2;
            int c0 = k0 + k;
            br[it*2]   = (c0     < F_TXN) ? w[(long)c0 * HID + n]       : 0.f;
            br[it*2+1] = (c0 + 1 < F_TXN) ? w[(long)(c0 + 1) * HID + n] : 0.f;
        }
    };

    auto write_lds = [&](int buf) {
        #pragma unroll
        for (int it = 0; it < 8; ++it) {
            int e = it * 512 + t * 2;
            int k = e & 31;
            int m = e >> 5;
            unsigned pk = (unsigned)f2bf(ar[it*2]) | ((unsigned)f2bf(ar[it*2+1]) << 16);
            *reinterpret_cast<unsigned*>(&Ash[buf][m][k]) = pk;
        }
        #pragma unroll
        for (int it = 0; it < 8; ++it) {
            int p = it * 256 + t;
            int n = p >> 4;
            int k = (p & 15) * 2;
            unsigned pk = (unsigned)f2bf(br[it*2]) | ((unsigned)f2bf(br[it*2+1]) << 16);
            *reinterpret_cast<unsigned*>(&Bsh[buf][n][k]) = pk;
        }
    };

    f32x4 acc[4][4];
    #pragma unroll
    for (int m = 0; m < 4; ++m)
        #pragma unroll
        for (int n = 0; n < 4; ++n)
            acc[m][n] = f32x4{0.f, 0.f, 0.f, 0.f};

    load_regs(0);
    write_lds(0);
    __syncthreads();

    int cur = 0;
    for (int step = 0; step < NSTEP; ++step) {
        if (step + 1 < NSTEP) load_regs(step + 1);   // prefetch next tile into regs

        const int g   = lane >> 4;       // k-group: k = g*8 .. g*8+7
        const int r16 = lane & 15;
        bf16x8 af[4], bf[4];
        #pragma unroll
        for (int m = 0; m < 4; ++m)
            af[m] = *reinterpret_cast<const bf16x8*>(&Ash[cur][wr*64 + m*16 + r16][g*8]);
        #pragma unroll
        for (int n = 0; n < 4; ++n)
            bf[n] = *reinterpret_cast<const bf16x8*>(&Bsh[cur][wc*64 + n*16 + r16][g*8]);
        #pragma unroll
        for (int m = 0; m < 4; ++m)
            #pragma unroll
            for (int n = 0; n < 4; ++n)
                acc[m][n] = __builtin_amdgcn_mfma_f32_16x16x32_bf16(af[m], bf[n], acc[m][n], 0, 0, 0);

        if (step + 1 < NSTEP) write_lds(cur ^ 1);
        __syncthreads();
        cur ^= 1;
    }

    // epilogue: C[row][col], col = lane&15 within 16-frag, row = (lane>>4)*4 + j
    const int r16 = lane & 15;
    const int g   = lane >> 4;
    #pragma unroll
    for (int n = 0; n < 4; ++n) {
        int col = wc*64 + n*16 + r16;
        float bv = bias[col];
        #pragma unroll
        for (int m = 0; m < 4; ++m) {
            int rbase = blockM + wr*64 + m*16 + g*4;
            #pragma unroll
            for (int j = 0; j < 4; ++j) {
                int row = rbase + j;
                if (row < N_TXN)
                    out[(long)(N_CAT + N_CONT + row) * HID + col] = acc[m][n][j] + bv;
            }
        }
    }
}

extern "C" void kernel_launch(void* const* d_in, const int* in_sizes, int n_in,
                              void* d_out, int out_size, void* d_ws, size_t ws_size,
                              hipStream_t stream) {
    const float* cat_tables   = (const float*)d_in[0];
    const float* cont_w       = (const float*)d_in[1];
    const float* cont_b       = (const float*)d_in[2];
    const float* txn_w        = (const float*)d_in[3];
    const float* txn_b        = (const float*)d_in[4];
    const float* txn_feats    = (const float*)d_in[5];
    const float* cont_values  = (const float*)d_in[6];
    const int*   cat_type_ids = (const int*)d_in[7];
    const int*   cat_value_ids= (const int*)d_in[8];
    const int*   cont_type_ids= (const int*)d_in[9];
    float* out = (float*)d_out;

    cat_kernel<<<(N_CAT * 32) / 256, 256, 0, stream>>>(cat_tables, cat_type_ids, cat_value_ids, out);
    cont_kernel<<<(N_CONT * 32) / 256, 256, 0, stream>>>(cont_w, cont_b, cont_values, cont_type_ids, out);
    txn_kernel<<<(N_TXN + BM - 1) / BM, 256, 0, stream>>>(txn_feats, txn_w, txn_b, out);
}

// Round 2
// 214.207 us; speedup vs baseline: 1.2142x; 1.2142x over previous
//
#include <hip/hip_runtime.h>

#define HID    128
#define VOCAB  1000
#define N_CAT  200000
#define N_CONT 150000
#define N_TXN  150000
#define F_TXN  371
#define KP     384                    // padded K in workspace B^T
#define OUT_TXN_BASE (N_CAT + N_CONT)

typedef __attribute__((ext_vector_type(4))) float f32x4;
typedef float f32x4u __attribute__((ext_vector_type(4), aligned(4)));  // may be 4B-aligned
typedef __attribute__((ext_vector_type(8))) short bf16x8;

__device__ __forceinline__ unsigned short f2bf(float x) {
    union { float f; unsigned u; } c; c.f = x;
    unsigned r = c.u + 0x7FFF + ((c.u >> 16) & 1);   // RNE
    return (unsigned short)(r >> 16);
}

__device__ __forceinline__ bf16x8 cvt8(f32x4 a, f32x4 b) {
    bf16x8 r;
    r[0] = (short)f2bf(a[0]); r[1] = (short)f2bf(a[1]);
    r[2] = (short)f2bf(a[2]); r[3] = (short)f2bf(a[3]);
    r[4] = (short)f2bf(b[0]); r[5] = (short)f2bf(b[1]);
    r[6] = (short)f2bf(b[2]); r[7] = (short)f2bf(b[3]);
    return r;
}

// ---- producer: Bt[col][k] = bf16(w[k][col]), zero-padded to KP ----
__global__ void bt_kernel(const float* __restrict__ w, unsigned short* __restrict__ bt) {
    int col = blockIdx.x;          // 0..127
    int k   = threadIdx.x;         // 0..383
    float v = (k < F_TXN) ? w[(long)k * HID + col] : 0.f;
    bt[col * KP + k] = f2bf(v);
}

// ---- fused cat gather + cont linear ----
#define CAT_BLOCKS  (N_CAT / 8)    // 25000 blocks of 256 threads, 8 rows each
#define CONT_BLOCKS (N_CONT / 8)   // 18750
__global__ __launch_bounds__(256) void catcont_kernel(
    const float* __restrict__ tables, const int* __restrict__ tids, const int* __restrict__ vids,
    const float* __restrict__ w, const float* __restrict__ b,
    const float* __restrict__ vals, const int* __restrict__ ctids,
    float* __restrict__ out)
{
    int bid = blockIdx.x;
    if (bid < CAT_BLOCKS) {
        int tid = bid * 256 + threadIdx.x;
        int row = tid >> 5;
        int h   = (tid & 31) << 2;
        long src = ((long)tids[row] * VOCAB + vids[row]) * HID + h;
        *reinterpret_cast<f32x4*>(out + (long)row * HID + h) =
            *reinterpret_cast<const f32x4*>(tables + src);
    } else {
        int tid = (bid - CAT_BLOCKS) * 256 + threadIdx.x;
        int row = tid >> 5;
        int h   = (tid & 31) << 2;
        int t   = ctids[row];
        float v = vals[row];
        f32x4 wv = *reinterpret_cast<const f32x4*>(w + t * HID + h);
        f32x4 bv = *reinterpret_cast<const f32x4*>(b + t * HID + h);
        f32x4 r  = v * wv + bv;
        *reinterpret_cast<f32x4*>(out + (long)(N_CAT + row) * HID + h) = r;
    }
}

// ---- txn GEMM: no LDS, no barriers; wave = 32 rows x 128 cols ----
__global__ __launch_bounds__(256, 3) void txn_kernel(
    const float* __restrict__ feats, const unsigned short* __restrict__ bt,
    const float* __restrict__ bias, float* __restrict__ out)
{
    const int lane = threadIdx.x & 63;
    const int tile = blockIdx.x * 4 + (threadIdx.x >> 6);   // one wave = one 32-row tile
    const int r16  = lane & 15;
    const int kg   = lane >> 4;            // k-group 0..3: k = kg*8 + i

    const int row0 = tile * 32 + r16;      // m-frag 0 row
    const int row1 = row0 + 16;            // m-frag 1 row
    const int r0c  = min(row0, N_TXN - 1);
    const int r1c  = min(row1, N_TXN - 1);

    const float* a0 = feats + (long)r0c * F_TXN + kg * 8;
    const float* a1 = feats + (long)r1c * F_TXN + kg * 8;
    const unsigned short* bp = bt + r16 * KP + kg * 8;

    f32x4 acc[2][8];
    #pragma unroll
    for (int m = 0; m < 2; ++m)
        #pragma unroll
        for (int nf = 0; nf < 8; ++nf)
            acc[m][nf] = f32x4{0.f, 0.f, 0.f, 0.f};

    #pragma unroll
    for (int s = 0; s < 12; ++s) {
        bf16x8 af0, af1;
        if (s < 11) {
            // all k in [s*32, s*32+32) < 371 for s<=10: clean vector loads
            f32x4 x0 = *reinterpret_cast<const f32x4u*>(a0 + s * 32);
            f32x4 x1 = *reinterpret_cast<const f32x4u*>(a0 + s * 32 + 4);
            f32x4 y0 = *reinterpret_cast<const f32x4u*>(a1 + s * 32);
            f32x4 y1 = *reinterpret_cast<const f32x4u*>(a1 + s * 32 + 4);
            af0 = cvt8(x0, x1);
            af1 = cvt8(y0, y1);
        } else {
            // tail step: k = 352 + kg*8 + i, valid while < 371 (B is zero-padded,
            // but A must not read past the buffer / inject NaN)
            float v0[8], v1[8];
            #pragma unroll
            for (int i = 0; i < 8; ++i) {
                int k = s * 32 + kg * 8 + i;
                bool ok = (k < F_TXN);
                v0[i] = ok ? a0[s * 32 + i] : 0.f;
                v1[i] = ok ? a1[s * 32 + i] : 0.f;
            }
            f32x4 x0{v0[0], v0[1], v0[2], v0[3]}, x1{v0[4], v0[5], v0[6], v0[7]};
            f32x4 y0{v1[0], v1[1], v1[2], v1[3]}, y1{v1[4], v1[5], v1[6], v1[7]};
            af0 = cvt8(x0, x1);
            af1 = cvt8(y0, y1);
        }

        const unsigned short* bs = bp + s * 32;
        #pragma unroll
        for (int nf = 0; nf < 8; ++nf) {
            bf16x8 bfrag = *reinterpret_cast<const bf16x8*>(bs + nf * 16 * KP);
            acc[0][nf] = __builtin_amdgcn_mfma_f32_16x16x32_bf16(af0, bfrag, acc[0][nf], 0, 0, 0);
            acc[1][nf] = __builtin_amdgcn_mfma_f32_16x16x32_bf16(af1, bfrag, acc[1][nf], 0, 0, 0);
        }
    }

    // epilogue: C row = kg*4 + j (+ m*16), col = nf*16 + r16
    #pragma unroll
    for (int nf = 0; nf < 8; ++nf) {
        int col = nf * 16 + r16;
        float bv = bias[col];
        #pragma unroll
        for (int m = 0; m < 2; ++m) {
            int rb = tile * 32 + m * 16 + kg * 4;
            #pragma unroll
            for (int j = 0; j < 4; ++j) {
                int r = rb + j;
                if (r < N_TXN)
                    out[(long)(OUT_TXN_BASE + r) * HID + col] = acc[m][nf][j] + bv;
            }
        }
    }
}

extern "C" void kernel_launch(void* const* d_in, const int* in_sizes, int n_in,
                              void* d_out, int out_size, void* d_ws, size_t ws_size,
                              hipStream_t stream) {
    const float* cat_tables    = (const float*)d_in[0];
    const float* cont_w        = (const float*)d_in[1];
    const float* cont_b        = (const float*)d_in[2];
    const float* txn_w         = (const float*)d_in[3];
    const float* txn_b         = (const float*)d_in[4];
    const float* txn_feats     = (const float*)d_in[5];
    const float* cont_values   = (const float*)d_in[6];
    const int*   cat_type_ids  = (const int*)d_in[7];
    const int*   cat_value_ids = (const int*)d_in[8];
    const int*   cont_type_ids = (const int*)d_in[9];
    float* out = (float*)d_out;
    unsigned short* bt = (unsigned short*)d_ws;   // 128*384*2 = 96 KB

    // 1) build bf16 B^T in workspace (txn kernel depends on it; same stream => ordered)
    bt_kernel<<<HID, KP, 0, stream>>>(txn_w, bt);

    // 2) txn GEMM: 4688 tiles of 32 rows, 4 waves per block
    const int tiles = (N_TXN + 31) / 32;           // 4688 (exact: 4687.5 -> guard rows)
    txn_kernel<<<(tiles + 3) / 4, 256, 0, stream>>>(txn_feats, bt, txn_b, out);

    // 3) fused cat + cont
    catcont_kernel<<<CAT_BLOCKS + CONT_BLOCKS, 256, 0, stream>>>(
        cat_tables, cat_type_ids, cat_value_ids,
        cont_w, cont_b, cont_values, cont_type_ids, out);
}

// Round 3
// 204.521 us; speedup vs baseline: 1.2718x; 1.0474x over previous
//
#include <hip/hip_runtime.h>

#define HID    128
#define VOCAB  1000
#define N_CAT  200000
#define N_CONT 150000
#define N_TXN  150000
#define F_TXN  371
#define KP     384                    // padded K in workspace B^T
#define BM     128
#define BK     32
#define NSTEP  12                     // 12*32 = 384 >= 371
#define OUT_TXN_BASE (N_CAT + N_CONT)
#define A_LIMIT ((unsigned)(N_TXN * F_TXN - 1))

typedef __attribute__((ext_vector_type(4))) float f32x4;
typedef __attribute__((ext_vector_type(8))) short bf16x8;

__device__ __forceinline__ unsigned short f2bf(float x) {
    union { float f; unsigned u; } c; c.f = x;
    unsigned r = c.u + 0x7FFF + ((c.u >> 16) & 1);   // RNE
    return (unsigned short)(r >> 16);
}

__device__ __forceinline__ bf16x8 cvt8(f32x4 a, f32x4 b) {
    bf16x8 r;
    r[0] = (short)f2bf(a[0]); r[1] = (short)f2bf(a[1]);
    r[2] = (short)f2bf(a[2]); r[3] = (short)f2bf(a[3]);
    r[4] = (short)f2bf(b[0]); r[5] = (short)f2bf(b[1]);
    r[6] = (short)f2bf(b[2]); r[7] = (short)f2bf(b[3]);
    return r;
}

// ---- producer: Bt[col][k] = bf16(w[k][col]), zero-padded to KP ----
__global__ void bt_kernel(const float* __restrict__ w, unsigned short* __restrict__ bt) {
    int col = blockIdx.x;          // 0..127
    int k   = threadIdx.x;         // 0..383
    float v = (k < F_TXN) ? w[(long)k * HID + col] : 0.f;
    bt[col * KP + k] = f2bf(v);
}

// ---- fused cat gather + cont linear ----
#define CAT_BLOCKS  (N_CAT / 8)    // 25000 blocks of 256 threads, 8 rows each
#define CONT_BLOCKS (N_CONT / 8)   // 18750
__global__ __launch_bounds__(256) void catcont_kernel(
    const float* __restrict__ tables, const int* __restrict__ tids, const int* __restrict__ vids,
    const float* __restrict__ w, const float* __restrict__ b,
    const float* __restrict__ vals, const int* __restrict__ ctids,
    float* __restrict__ out)
{
    int bid = blockIdx.x;
    if (bid < CAT_BLOCKS) {
        int tid = bid * 256 + threadIdx.x;
        int row = tid >> 5;
        int h   = (tid & 31) << 2;
        long src = ((long)tids[row] * VOCAB + vids[row]) * HID + h;
        *reinterpret_cast<f32x4*>(out + (long)row * HID + h) =
            *reinterpret_cast<const f32x4*>(tables + src);
    } else {
        int tid = (bid - CAT_BLOCKS) * 256 + threadIdx.x;
        int row = tid >> 5;
        int h   = (tid & 31) << 2;
        int t   = ctids[row];
        float v = vals[row];
        f32x4 wv = *reinterpret_cast<const f32x4*>(w + t * HID + h);
        f32x4 bv = *reinterpret_cast<const f32x4*>(b + t * HID + h);
        f32x4 r  = v * wv + bv;
        *reinterpret_cast<f32x4*>(out + (long)(N_CAT + row) * HID + h) = r;
    }
}

// ---- txn GEMM: async LDS-staged A (f32, source-swizzled), reg-direct B ----
__global__ __launch_bounds__(256, 3) void txn_kernel(
    const float* __restrict__ feats, const unsigned short* __restrict__ bt,
    const float* __restrict__ bias, float* __restrict__ out)
{
    __shared__ float Ash[2][BM * BK];   // 2 x 16 KB; [row][k^swz] layout

    const int t    = threadIdx.x;
    const int lane = t & 63;
    const int w    = t >> 6;            // wave 0..3, owns rows [w*32, w*32+32)
    const int r16  = lane & 15;
    const int kg   = lane >> 4;         // k-group: k = kg*8 + i
    const long blockM = (long)blockIdx.x * BM;

    // Precompute staging source offsets (elements), row-clamped.
    // LDS dword d = it*256 + t holds A[row][k] with row=d>>5,
    // k = (d&31) ^ ((row&7)<<2)  (source pre-swizzle; LDS write is linear).
    unsigned base_e[16];
    #pragma unroll
    for (int it = 0; it < 16; ++it) {
        int d   = it * 256 + t;
        int row = d >> 5;
        int k   = (d & 31) ^ ((row & 7) << 2);
        long rg = blockM + row;
        if (rg > N_TXN - 1) rg = N_TXN - 1;     // last-block guard (rows masked at store)
        base_e[it] = (unsigned)(rg * F_TXN + k);
    }

    auto stage = [&](int buf, int s) {
        const unsigned k0 = (unsigned)(s * BK);
        const bool tail = (s == NSTEP - 1);
        #pragma unroll
        for (int it = 0; it < 16; ++it) {
            unsigned gofs = base_e[it] + k0;
            if (tail && gofs > A_LIMIT) gofs = A_LIMIT;   // k>=371 garbage is killed by B=0
            float* ldst = &Ash[buf][it * 256 + w * 64];   // wave-uniform base; +lane*4 by HW
            __builtin_amdgcn_global_load_lds(
                (const __attribute__((address_space(1))) unsigned int*)(feats + gofs),
                (__attribute__((address_space(3))) unsigned int*)ldst,
                4, 0, 0);
        }
    };

    f32x4 acc[2][8];
    #pragma unroll
    for (int mf = 0; mf < 2; ++mf)
        #pragma unroll
        for (int nf = 0; nf < 8; ++nf)
            acc[mf][nf] = f32x4{0.f, 0.f, 0.f, 0.f};

    const unsigned short* bp = bt + r16 * KP + kg * 8;

    stage(0, 0);
    __syncthreads();   // compiler emits vmcnt(0) drain + barrier

    int cur = 0;
    #pragma unroll 1
    for (int s = 0; s < NSTEP; ++s) {
        if (s + 1 < NSTEP) stage(cur ^ 1, s + 1);   // async prefetch under compute

        // A fragments: 8 f32 -> bf16x8, swizzled ds_read_b128 pair
        bf16x8 af[2];
        #pragma unroll
        for (int mf = 0; mf < 2; ++mf) {
            int row = w * 32 + mf * 16 + r16;
            int sw  = (row & 7) << 4;
            const char* base = (const char*)&Ash[cur][0] + row * 128;
            f32x4 lo = *reinterpret_cast<const f32x4*>(base + ((kg * 32)      ^ sw));
            f32x4 hi = *reinterpret_cast<const f32x4*>(base + ((kg * 32 + 16) ^ sw));
            af[mf] = cvt8(lo, hi);
        }

        const unsigned short* bs = bp + s * 32;
        #pragma unroll
        for (int nf = 0; nf < 8; ++nf) {
            bf16x8 bfrag = *reinterpret_cast<const bf16x8*>(bs + (long)nf * 16 * KP);
            acc[0][nf] = __builtin_amdgcn_mfma_f32_16x16x32_bf16(af[0], bfrag, acc[0][nf], 0, 0, 0);
            acc[1][nf] = __builtin_amdgcn_mfma_f32_16x16x32_bf16(af[1], bfrag, acc[1][nf], 0, 0, 0);
        }

        __syncthreads();   // drains staging of buf^1 + separates LDS reuse
        cur ^= 1;
    }

    // epilogue: C row = kg*4 + j (+ mf*16 + w*32), col = nf*16 + r16
    #pragma unroll
    for (int nf = 0; nf < 8; ++nf) {
        int col = nf * 16 + r16;
        float bv = bias[col];
        #pragma unroll
        for (int mf = 0; mf < 2; ++mf) {
            long rb = blockM + w * 32 + mf * 16 + kg * 4;
            #pragma unroll
            for (int j = 0; j < 4; ++j) {
                long r = rb + j;
                if (r < N_TXN)
                    out[(OUT_TXN_BASE + r) * HID + col] = acc[mf][nf][j] + bv;
            }
        }
    }
}

extern "C" void kernel_launch(void* const* d_in, const int* in_sizes, int n_in,
                              void* d_out, int out_size, void* d_ws, size_t ws_size,
                              hipStream_t stream) {
    const float* cat_tables    = (const float*)d_in[0];
    const float* cont_w        = (const float*)d_in[1];
    const float* cont_b        = (const float*)d_in[2];
    const float* txn_w         = (const float*)d_in[3];
    const float* txn_b         = (const float*)d_in[4];
    const float* txn_feats     = (const float*)d_in[5];
    const float* cont_values   = (const float*)d_in[6];
    const int*   cat_type_ids  = (const int*)d_in[7];
    const int*   cat_value_ids = (const int*)d_in[8];
    const int*   cont_type_ids = (const int*)d_in[9];
    float* out = (float*)d_out;
    unsigned short* bt = (unsigned short*)d_ws;   // 128*384*2 = 96 KB

    bt_kernel<<<HID, KP, 0, stream>>>(txn_w, bt);

    const int blocks = (N_TXN + BM - 1) / BM;     // 1172
    txn_kernel<<<blocks, 256, 0, stream>>>(txn_feats, bt, txn_b, out);

    catcont_kernel<<<CAT_BLOCKS + CONT_BLOCKS, 256, 0, stream>>>(
        cat_tables, cat_type_ids, cat_value_ids,
        cont_w, cont_b, cont_values, cont_type_ids, out);
}

// Round 4
// 194.152 us; speedup vs baseline: 1.3397x; 1.0534x over previous
//
#include <hip/hip_runtime.h>

#define HID    128
#define VOCAB  1000
#define N_CAT  200000
#define N_CONT 150000
#define N_TXN  150000
#define F_TXN  371
#define KP     384
#define BM     128
#define NSTEP  12                     // 12*32 = 384 >= 371
#define NTILE  ((N_TXN + BM - 1) / BM)   // 1172
#define OUT_TXN_BASE (N_CAT + N_CONT)
#define A_LIMIT ((unsigned)(N_TXN * F_TXN - 1))

// ---- fast-path workspace layout ----
#define AWK_CHUNKS (NTILE * NSTEP * BM * 4)          // 7,200,768 x 16B chunks
#define AWK_BYTES  ((size_t)AWK_CHUNKS * 16)         // 115,212,288
#define BT2_ELEMS  (NSTEP * 128 * 32)                // 49,152 bf16
#define BT2_BYTES  ((size_t)BT2_ELEMS * 2)           // 98,304
#define WS_NEEDED  (AWK_BYTES + BT2_BYTES)

typedef __attribute__((ext_vector_type(4))) float f32x4;
typedef float f32x4u __attribute__((ext_vector_type(4), aligned(4)));
typedef __attribute__((ext_vector_type(8))) short bf16x8;

__device__ __forceinline__ unsigned short f2bf(float x) {
    union { float f; unsigned u; } c; c.f = x;
    unsigned r = c.u + 0x7FFF + ((c.u >> 16) & 1);   // RNE
    return (unsigned short)(r >> 16);
}

__device__ __forceinline__ bf16x8 cvt8(f32x4 a, f32x4 b) {
    bf16x8 r;
    r[0] = (short)f2bf(a[0]); r[1] = (short)f2bf(a[1]);
    r[2] = (short)f2bf(a[2]); r[3] = (short)f2bf(a[3]);
    r[4] = (short)f2bf(b[0]); r[5] = (short)f2bf(b[1]);
    r[6] = (short)f2bf(b[2]); r[7] = (short)f2bf(b[3]);
    return r;
}

// ================= fused cat gather + cont linear =================
#define CAT_BLOCKS  (N_CAT / 8)
#define CONT_BLOCKS (N_CONT / 8)
__global__ __launch_bounds__(256) void catcont_kernel(
    const float* __restrict__ tables, const int* __restrict__ tids, const int* __restrict__ vids,
    const float* __restrict__ w, const float* __restrict__ b,
    const float* __restrict__ vals, const int* __restrict__ ctids,
    float* __restrict__ out)
{
    int bid = blockIdx.x;
    if (bid < CAT_BLOCKS) {
        int tid = bid * 256 + threadIdx.x;
        int row = tid >> 5;
        int h   = (tid & 31) << 2;
        long src = ((long)tids[row] * VOCAB + vids[row]) * HID + h;
        *reinterpret_cast<f32x4*>(out + (long)row * HID + h) =
            *reinterpret_cast<const f32x4*>(tables + src);
    } else {
        int tid = (bid - CAT_BLOCKS) * 256 + threadIdx.x;
        int row = tid >> 5;
        int h   = (tid & 31) << 2;
        int t   = ctids[row];
        float v = vals[row];
        f32x4 wv = *reinterpret_cast<const f32x4*>(w + t * HID + h);
        f32x4 bv = *reinterpret_cast<const f32x4*>(b + t * HID + h);
        f32x4 r  = v * wv + bv;
        *reinterpret_cast<f32x4*>(out + (long)(N_CAT + row) * HID + h) = r;
    }
}

// ================= FAST PATH =================
// A repacked to bf16 in per-(tile,step) LDS-image order, bank-swizzle baked in.
// chunk p -> (tile t, step s, row r, write-chunk kg_w); content k-group kg = kg_w ^ ((r>>1)&3)
__global__ __launch_bounds__(256) void awk_kernel(
    const float* __restrict__ feats, unsigned short* __restrict__ awk)
{
    unsigned p    = blockIdx.x * 256 + threadIdx.x;     // < AWK_CHUNKS
    unsigned kg_w = p & 3;
    unsigned r    = (p >> 2) & 127;
    unsigned ts   = p >> 9;                             // t*12 + s
    unsigned s    = ts % 12u;
    unsigned t    = ts / 12u;
    unsigned kg   = kg_w ^ ((r >> 1) & 3);
    long     R    = (long)t * BM + r;
    int      k0   = (int)(s * 32 + kg * 8);

    bf16x8 v;
    if (R < N_TXN && k0 + 8 <= F_TXN) {
        const float* src = feats + R * F_TXN + k0;
        f32x4 a = *reinterpret_cast<const f32x4u*>(src);
        f32x4 b = *reinterpret_cast<const f32x4u*>(src + 4);
        v = cvt8(a, b);
    } else if (R < N_TXN && k0 < F_TXN) {
        #pragma unroll
        for (int j = 0; j < 8; ++j)
            v[j] = (k0 + j < F_TXN) ? (short)f2bf(feats[R * F_TXN + k0 + j]) : (short)0;
    } else {
        #pragma unroll
        for (int j = 0; j < 8; ++j) v[j] = 0;
    }
    *reinterpret_cast<bf16x8*>(awk + (size_t)p * 8) = v;
}

// W repacked likewise: per step 8KB contiguous, [col][chunk] with chunk swizzle.
__global__ __launch_bounds__(256) void bt2_kernel(
    const float* __restrict__ w, unsigned short* __restrict__ bt2)
{
    unsigned p    = blockIdx.x * 256 + threadIdx.x;     // < 6144
    unsigned kg_w = p & 3;
    unsigned col  = (p >> 2) & 127;
    unsigned s    = p >> 9;                             // 0..11
    unsigned kg   = kg_w ^ ((col >> 1) & 3);
    int      k0   = (int)(s * 32 + kg * 8);
    bf16x8 v;
    #pragma unroll
    for (int j = 0; j < 8; ++j)
        v[j] = (k0 + j < F_TXN) ? (short)f2bf(w[(long)(k0 + j) * HID + col]) : (short)0;
    *reinterpret_cast<bf16x8*>(bt2 + (size_t)p * 8) = v;
}

// m97-style GEMM: contiguous width-16 global_load_lds, 1 full-drain barrier/step.
__global__ __launch_bounds__(256) void txn2_kernel(
    const unsigned short* __restrict__ awk, const unsigned short* __restrict__ bt2,
    const float* __restrict__ bias, float* __restrict__ out)
{
    __shared__ __align__(16) unsigned short Ash[2][4096];   // [row][32k] bf16, 64B rows
    __shared__ __align__(16) unsigned short Bsh[2][4096];   // [col][32k]

    const int t    = threadIdx.x;
    const int lane = t & 63;
    const int w    = t >> 6;
    const int r16  = lane & 15;
    const int kg   = lane >> 4;
    const long blockM = (long)blockIdx.x * BM;
    const unsigned short* abase = awk + (size_t)blockIdx.x * (NSTEP * 4096);

    auto stage = [&](int buf, int s) {
        #pragma unroll
        for (int i = 0; i < 2; ++i) {
            int eo = w * 1024 + i * 512;   // element offset in the 4096-elem tile image
            __builtin_amdgcn_global_load_lds(
                (const __attribute__((address_space(1))) unsigned int*)(abase + s * 4096 + eo + lane * 8),
                (__attribute__((address_space(3))) unsigned int*)&Ash[buf][eo], 16, 0, 0);
            __builtin_amdgcn_global_load_lds(
                (const __attribute__((address_space(1))) unsigned int*)(bt2 + s * 4096 + eo + lane * 8),
                (__attribute__((address_space(3))) unsigned int*)&Bsh[buf][eo], 16, 0, 0);
        }
    };

    f32x4 acc[2][8];
    #pragma unroll
    for (int mf = 0; mf < 2; ++mf)
        #pragma unroll
        for (int nf = 0; nf < 8; ++nf)
            acc[mf][nf] = f32x4{0.f, 0.f, 0.f, 0.f};

    stage(0, 0);
    __syncthreads();

    int cur = 0;
    #pragma unroll 1
    for (int s = 0; s < NSTEP; ++s) {
        if (s + 1 < NSTEP) stage(cur ^ 1, s + 1);

        bf16x8 af[2], bfr[8];
        #pragma unroll
        for (int mf = 0; mf < 2; ++mf) {
            int row = w * 32 + mf * 16 + r16;
            af[mf] = *reinterpret_cast<const bf16x8*>(
                &Ash[cur][row * 32 + ((kg ^ ((row >> 1) & 3)) * 8)]);
        }
        #pragma unroll
        for (int nf = 0; nf < 8; ++nf) {
            int col = nf * 16 + r16;
            bfr[nf] = *reinterpret_cast<const bf16x8*>(
                &Bsh[cur][col * 32 + ((kg ^ ((col >> 1) & 3)) * 8)]);
        }
        #pragma unroll
        for (int nf = 0; nf < 8; ++nf) {
            acc[0][nf] = __builtin_amdgcn_mfma_f32_16x16x32_bf16(af[0], bfr[nf], acc[0][nf], 0, 0, 0);
            acc[1][nf] = __builtin_amdgcn_mfma_f32_16x16x32_bf16(af[1], bfr[nf], acc[1][nf], 0, 0, 0);
        }

        __syncthreads();
        cur ^= 1;
    }

    #pragma unroll
    for (int nf = 0; nf < 8; ++nf) {
        int col = nf * 16 + r16;
        float bv = bias[col];
        #pragma unroll
        for (int mf = 0; mf < 2; ++mf) {
            long rb = blockM + w * 32 + mf * 16 + kg * 4;
            #pragma unroll
            for (int j = 0; j < 4; ++j) {
                long r = rb + j;
                if (r < N_TXN)
                    out[(OUT_TXN_BASE + r) * HID + col] = acc[mf][nf][j] + bv;
            }
        }
    }
}

// ================= FALLBACK PATH (validated round-3 kernels) =================
__global__ void bt_kernel(const float* __restrict__ w, unsigned short* __restrict__ bt) {
    int col = blockIdx.x;
    int k   = threadIdx.x;
    float v = (k < F_TXN) ? w[(long)k * HID + col] : 0.f;
    bt[col * KP + k] = f2bf(v);
}

__global__ __launch_bounds__(256, 3) void txn_kernel(
    const float* __restrict__ feats, const unsigned short* __restrict__ bt,
    const float* __restrict__ bias, float* __restrict__ out)
{
    __shared__ float Ash[2][BM * 32];

    const int t    = threadIdx.x;
    const int lane = t & 63;
    const int w    = t >> 6;
    const int r16  = lane & 15;
    const int kg   = lane >> 4;
    const long blockM = (long)blockIdx.x * BM;

    unsigned base_e[16];
    #pragma unroll
    for (int it = 0; it < 16; ++it) {
        int d   = it * 256 + t;
        int row = d >> 5;
        int k   = (d & 31) ^ ((row & 7) << 2);
        long rg = blockM + row;
        if (rg > N_TXN - 1) rg = N_TXN - 1;
        base_e[it] = (unsigned)(rg * F_TXN + k);
    }

    auto stage = [&](int buf, int s) {
        const unsigned k0 = (unsigned)(s * 32);
        const bool tail = (s == NSTEP - 1);
        #pragma unroll
        for (int it = 0; it < 16; ++it) {
            unsigned gofs = base_e[it] + k0;
            if (tail && gofs > A_LIMIT) gofs = A_LIMIT;
            float* ldst = &Ash[buf][it * 256 + w * 64];
            __builtin_amdgcn_global_load_lds(
                (const __attribute__((address_space(1))) unsigned int*)(feats + gofs),
                (__attribute__((address_space(3))) unsigned int*)ldst, 4, 0, 0);
        }
    };

    f32x4 acc[2][8];
    #pragma unroll
    for (int mf = 0; mf < 2; ++mf)
        #pragma unroll
        for (int nf = 0; nf < 8; ++nf)
            acc[mf][nf] = f32x4{0.f, 0.f, 0.f, 0.f};

    const unsigned short* bp = bt + r16 * KP + kg * 8;

    stage(0, 0);
    __syncthreads();

    int cur = 0;
    #pragma unroll 1
    for (int s = 0; s < NSTEP; ++s) {
        if (s + 1 < NSTEP) stage(cur ^ 1, s + 1);

        bf16x8 af[2];
        #pragma unroll
        for (int mf = 0; mf < 2; ++mf) {
            int row = w * 32 + mf * 16 + r16;
            int sw  = (row & 7) << 4;
            const char* base = (const char*)&Ash[cur][0] + row * 128;
            f32x4 lo = *reinterpret_cast<const f32x4*>(base + ((kg * 32)      ^ sw));
            f32x4 hi = *reinterpret_cast<const f32x4*>(base + ((kg * 32 + 16) ^ sw));
            af[mf] = cvt8(lo, hi);
        }

        const unsigned short* bs = bp + s * 32;
        #pragma unroll
        for (int nf = 0; nf < 8; ++nf) {
            bf16x8 bfrag = *reinterpret_cast<const bf16x8*>(bs + (long)nf * 16 * KP);
            acc[0][nf] = __builtin_amdgcn_mfma_f32_16x16x32_bf16(af[0], bfrag, acc[0][nf], 0, 0, 0);
            acc[1][nf] = __builtin_amdgcn_mfma_f32_16x16x32_bf16(af[1], bfrag, acc[1][nf], 0, 0, 0);
        }

        __syncthreads();
        cur ^= 1;
    }

    #pragma unroll
    for (int nf = 0; nf < 8; ++nf) {
        int col = nf * 16 + r16;
        float bv = bias[col];
        #pragma unroll
        for (int mf = 0; mf < 2; ++mf) {
            long rb = blockM + w * 32 + mf * 16 + kg * 4;
            #pragma unroll
            for (int j = 0; j < 4; ++j) {
                long r = rb + j;
                if (r < N_TXN)
                    out[(OUT_TXN_BASE + r) * HID + col] = acc[mf][nf][j] + bv;
            }
        }
    }
}

extern "C" void kernel_launch(void* const* d_in, const int* in_sizes, int n_in,
                              void* d_out, int out_size, void* d_ws, size_t ws_size,
                              hipStream_t stream) {
    const float* cat_tables    = (const float*)d_in[0];
    const float* cont_w        = (const float*)d_in[1];
    const float* cont_b        = (const float*)d_in[2];
    const float* txn_w         = (const float*)d_in[3];
    const float* txn_b         = (const float*)d_in[4];
    const float* txn_feats     = (const float*)d_in[5];
    const float* cont_values   = (const float*)d_in[6];
    const int*   cat_type_ids  = (const int*)d_in[7];
    const int*   cat_value_ids = (const int*)d_in[8];
    const int*   cont_type_ids = (const int*)d_in[9];
    float* out = (float*)d_out;

    if (ws_size >= WS_NEEDED) {
        unsigned short* awk = (unsigned short*)d_ws;
        unsigned short* bt2 = (unsigned short*)((char*)d_ws + AWK_BYTES);
        bt2_kernel<<<(NSTEP * 128 * 4) / 256, 256, 0, stream>>>(txn_w, bt2);
        awk_kernel<<<AWK_CHUNKS / 256, 256, 0, stream>>>(txn_feats, awk);
        txn2_kernel<<<NTILE, 256, 0, stream>>>(awk, bt2, txn_b, out);
    } else {
        unsigned short* bt = (unsigned short*)d_ws;
        bt_kernel<<<HID, KP, 0, stream>>>(txn_w, bt);
        txn_kernel<<<NTILE, 256, 0, stream>>>(txn_feats, bt, txn_b, out);
    }

    catcont_kernel<<<CAT_BLOCKS + CONT_BLOCKS, 256, 0, stream>>>(
        cat_tables, cat_type_ids, cat_value_ids,
        cont_w, cont_b, cont_values, cont_type_ids, out);
}